// Round 1
// 834.822 us; speedup vs baseline: 1.0785x; 1.0785x over previous
//
#include <hip/hip_runtime.h>

// NonMaximaSuppression2d: out = x * (x > max over 3x3 neighborhood excluding
// center), replicate ("edge") padding. Input fp32 (8,4,2048,2048).
//
// v2: 4-row register blocking + shuffle-based horizontal neighbors.
//  - Each thread computes a 4-row x 4-col (float4) tile: loads 6 rows once
//    (vertical amplification 1.5x instead of 3x, VMEM instrs per output row
//    10 -> 2.5).
//  - Left/right edge taps come from neighbor lanes via __shfl (LDS pipe)
//    instead of 16B-strided scalar global loads (which cost a full wave of
//    line transactions each). Only lanes 0/63 do a predicated scalar load.
//  - Clamped row/col indices reproduce replicate padding exactly (border
//    pixels compare against themselves -> output 0, matching reference).

#define IMG_H 2048
#define IMG_W 2048
#define ROWS 4  // output rows per thread

__global__ __launch_bounds__(256) void nms2d_kernel(const float* __restrict__ x,
                                                    float* __restrict__ out) {
    const int wq   = IMG_W / 4;      // 512 float4 groups per row
    const int segs = wq / 256;       // 2 blocks span one image row

    int seg   = blockIdx.x % segs;
    int rest  = blockIdx.x / segs;
    int rowg  = rest % (IMG_H / ROWS);
    int plane = rest / (IMG_H / ROWS);

    int col4 = seg * 256 + threadIdx.x;  // this thread's float4 column
    int c0   = col4 * 4;
    int r0   = rowg * ROWS;
    int lane = threadIdx.x & 63;

    const float* p = x   + (size_t)plane * IMG_H * IMG_W;
    float*       o = out + (size_t)plane * IMG_H * IMG_W;

    // ---- load 6 rows (r0-1 .. r0+ROWS), row-clamped (replicate padding) ----
    float4 v[ROWS + 2];
    int    rr[ROWS + 2];
    #pragma unroll
    for (int j = 0; j < ROWS + 2; ++j) {
        int r = r0 - 1 + j;
        r = r < 0 ? 0 : (r > IMG_H - 1 ? IMG_H - 1 : r);
        rr[j] = r;
        v[j] = *(const float4*)(p + (size_t)r * IMG_W + c0);
    }

    // ---- horizontal neighbors: shuffle from adjacent lanes ----
    float lv[ROWS + 2], rv[ROWS + 2];
    #pragma unroll
    for (int j = 0; j < ROWS + 2; ++j) {
        lv[j] = __shfl(v[j].w, lane - 1);  // lane-1's last element
        rv[j] = __shfl(v[j].x, lane + 1);  // lane+1's first element
    }
    // wave-boundary lanes: fetch from global (L1/L2 hit) or clamp at image edge
    if (lane == 0) {
        #pragma unroll
        for (int j = 0; j < ROWS + 2; ++j)
            lv[j] = (c0 > 0) ? p[(size_t)rr[j] * IMG_W + (c0 - 1)] : v[j].x;
    }
    if (lane == 63) {
        #pragma unroll
        for (int j = 0; j < ROWS + 2; ++j)
            rv[j] = (c0 + 4 < IMG_W) ? p[(size_t)rr[j] * IMG_W + (c0 + 4)] : v[j].w;
    }

    // ---- per-row full 3-wide horizontal max (used as top/bottom row max) ----
    float h[ROWS + 2][4];
    #pragma unroll
    for (int j = 0; j < ROWS + 2; ++j) {
        h[j][0] = fmaxf(fmaxf(lv[j],   v[j].x), v[j].y);
        h[j][1] = fmaxf(fmaxf(v[j].x,  v[j].y), v[j].z);
        h[j][2] = fmaxf(fmaxf(v[j].y,  v[j].z), v[j].w);
        h[j][3] = fmaxf(fmaxf(v[j].z,  v[j].w), rv[j]);
    }

    // ---- 4 output rows ----
    #pragma unroll
    for (int i = 0; i < ROWS; ++i) {
        const int j = i + 1;  // center row index into v/h
        // middle row: left+right only (center excluded)
        float m0 = fmaxf(lv[j],   v[j].y);
        float m1 = fmaxf(v[j].x,  v[j].z);
        float m2 = fmaxf(v[j].y,  v[j].w);
        float m3 = fmaxf(v[j].z,  rv[j]);

        float x0 = fmaxf(fmaxf(h[j - 1][0], h[j + 1][0]), m0);
        float x1 = fmaxf(fmaxf(h[j - 1][1], h[j + 1][1]), m1);
        float x2 = fmaxf(fmaxf(h[j - 1][2], h[j + 1][2]), m2);
        float x3 = fmaxf(fmaxf(h[j - 1][3], h[j + 1][3]), m3);

        float4 r;
        r.x = (v[j].x > x0) ? v[j].x : 0.0f;
        r.y = (v[j].y > x1) ? v[j].y : 0.0f;
        r.z = (v[j].z > x2) ? v[j].z : 0.0f;
        r.w = (v[j].w > x3) ? v[j].w : 0.0f;

        *(float4*)(o + (size_t)(r0 + i) * IMG_W + c0) = r;
    }
}

extern "C" void kernel_launch(void* const* d_in, const int* in_sizes, int n_in,
                              void* d_out, int out_size, void* d_ws, size_t ws_size,
                              hipStream_t stream) {
    const float* x = (const float*)d_in[0];
    float* out = (float*)d_out;
    int nplanes = in_sizes[0] / (IMG_H * IMG_W);  // 8*4 = 32

    const int segs = (IMG_W / 4) / 256;  // 2
    long long blocks = (long long)nplanes * (IMG_H / ROWS) * segs;
    nms2d_kernel<<<(int)blocks, 256, 0, stream>>>(x, out);
}